// Round 17
// baseline (69.772 us; speedup 1.0000x reference)
//
#include <hip/hip_runtime.h>
#include <stdint.h>

#define BB 4
#define NN 2048
#define F_IN 128
#define F_OUT 256
#define NH 4
#define HD 64

typedef float f32x4 __attribute__((ext_vector_type(4)));
typedef float f32x2 __attribute__((ext_vector_type(2)));
typedef short s16x8 __attribute__((ext_vector_type(8)));
typedef int i32x4 __attribute__((ext_vector_type(4)));
typedef unsigned long long u64;
typedef unsigned short u16;

#define LOG2E 1.4426950408889634f

__device__ __forceinline__ u16 f32_to_bf16_rtn(float f) {
    union { float f; uint32_t u; } v; v.f = f;
    uint32_t u = v.u;
    u += 0x7fffu + ((u >> 16) & 1u);
    return (u16)(u >> 16);
}

__device__ __forceinline__ float exp2_fast(float x) {
#if __has_builtin(__builtin_amdgcn_exp2f)
    return __builtin_amdgcn_exp2f(x);
#else
    return exp2f(x);
#endif
}

__device__ __forceinline__ int sbfe1(uint32_t v, int k) {
#if __has_builtin(__builtin_amdgcn_sbfe)
    return __builtin_amdgcn_sbfe((int)v, k, 1);   // bit k sign-extended: 0 or -1
#else
    return ((int32_t)(v << (31 - k))) >> 31;
#endif
}

// K0: standalone adj-pack, dwordx4 loads, ballot-free, shfl OR-tree.
__global__ __launch_bounds__(256) void k0_pack(
    const int* __restrict__ adj, uint32_t* __restrict__ abits32)
{
    const int t = threadIdx.x;
    const int row = (blockIdx.x << 2) | (t >> 6);
    const int l = t & 63;
    const i32x4* rowp = (const i32x4*)(adj + (size_t)row * NN) + l;
    i32x4 v[8];
#pragma unroll
    for (int u = 0; u < 8; ++u) v[u] = rowp[u * 64];   // all 8 in flight
    const int sh = (l & 7) * 4;
    uint32_t w[8];
#pragma unroll
    for (int u = 0; u < 8; ++u) {
        uint32_t nib = (uint32_t)(v[u][0] != 0)
                     | ((uint32_t)(v[u][1] != 0) << 1)
                     | ((uint32_t)(v[u][2] != 0) << 2)
                     | ((uint32_t)(v[u][3] != 0) << 3);
        uint32_t x = nib << sh;
        x |= __shfl_xor(x, 1, 64);
        x |= __shfl_xor(x, 2, 64);
        x |= __shfl_xor(x, 4, 64);
        w[u] = x;
    }
    abits32[(size_t)row * 64 + (l & 7) * 8 + (l >> 3)] = w[l & 7];
}

// K1: projection h = x @ W^T (fp32), 16-row tiles, 512 blocks.
// x is read DIRECTLY from global with block-uniform addresses (-> s_load /
// scalar cache; the 8 KB tile is sL1/vL1-resident). NO LDS staging of x —
// the previous version's 512 broadcast ds_read_b128/thread serialized the
// CU-shared LDS pipe (~20 us). LDS used only for the small el/er reduce.
__global__ __launch_bounds__(256) void k1_proj(
    const float* __restrict__ x, const float* __restrict__ W,
    const float* __restrict__ a_l, const float* __restrict__ a_r,
    u16* __restrict__ hB, float* __restrict__ el, f32x2* __restrict__ er12)
{
    const int t = threadIdx.x;

    __shared__ __align__(16) float red[4 * 64 * 20];   // 20 KB reduce buffer

    const int b = blockIdx.x >> 7;
    const int n0 = (blockIdx.x & 127) * 16;
    const float* xbase = x + ((size_t)b * NN + n0) * F_IN;   // block-uniform

    float acc[16];
#pragma unroll
    for (int n = 0; n < 16; ++n) acc[n] = 0.f;

    const float* wrow = W + (size_t)t * F_IN;
#pragma unroll 2
    for (int k0 = 0; k0 < F_IN; k0 += 8) {
        f32x4 w0 = *(const f32x4*)(wrow + k0);
        f32x4 w1 = *(const f32x4*)(wrow + k0 + 4);
#pragma unroll
        for (int n = 0; n < 16; ++n) {
            f32x4 xa = *(const f32x4*)(xbase + n * F_IN + k0);     // uniform
            f32x4 xb = *(const f32x4*)(xbase + n * F_IN + k0 + 4); // uniform
            float s = acc[n];
            s = fmaf(xa[0], w0[0], s); s = fmaf(xa[1], w0[1], s);
            s = fmaf(xa[2], w0[2], s); s = fmaf(xa[3], w0[3], s);
            s = fmaf(xb[0], w1[0], s); s = fmaf(xb[1], w1[1], s);
            s = fmaf(xb[2], w1[2], s); s = fmaf(xb[3], w1[3], s);
            acc[n] = s;
        }
    }

    const int w = t >> 6, lane = t & 63;
    const float al = a_l[t];
    const float ar = a_r[t];
    const int n_ = lane & 15, og = lane >> 4;
    float sl, sr;
    // l pass
    {
        float* rp = &red[((size_t)w * 64 + lane) * 20];
#pragma unroll
        for (int q = 0; q < 4; ++q) {
            f32x4 v;
#pragma unroll
            for (int e = 0; e < 4; ++e) v[e] = acc[q * 4 + e] * al;
            *(f32x4*)(rp + q * 4) = v;
        }
    }
    __syncthreads();
    {
        float s = 0.f;
#pragma unroll
        for (int oo = 0; oo < 16; ++oo)
            s += red[((size_t)w * 64 + og + 4 * oo) * 20 + n_];
        s += __shfl_xor(s, 16, 64); s += __shfl_xor(s, 32, 64);
        sl = s;
    }
    __syncthreads();
    // r pass (reuse buffer)
    {
        float* rp = &red[((size_t)w * 64 + lane) * 20];
#pragma unroll
        for (int q = 0; q < 4; ++q) {
            f32x4 v;
#pragma unroll
            for (int e = 0; e < 4; ++e) v[e] = acc[q * 4 + e] * ar;
            *(f32x4*)(rp + q * 4) = v;
        }
    }
    __syncthreads();
    {
        float s = 0.f;
#pragma unroll
        for (int oo = 0; oo < 16; ++oo)
            s += red[((size_t)w * 64 + og + 4 * oo) * 20 + n_];
        s += __shfl_xor(s, 16, 64); s += __shfl_xor(s, 32, 64);
        sr = s;
    }
    if (lane < 16) {
        el[((size_t)b * NH + w) * NN + n0 + lane] = sl * LOG2E;
        float sre = sr * LOG2E;
        f32x2 v2; v2[0] = exp2_fast(sre); v2[1] = exp2_fast(0.2f * sre);
        er12[((size_t)b * NH + w) * NN + n0 + lane] = v2;
    }

    // B-fragment layout store: hB[b][jt32][head][cb][lane64][8] (bf16)
    const int dcol = t & 15, cb = (t >> 4) & 3;
    const int jt32 = n0 >> 5;
    const int lb = dcol + ((n0 >> 3) & 2) * 16;
    u16* hb = hB + ((((size_t)b * 64 + jt32) * 4 + w) * 4 + cb) * 512 + (size_t)lb * 8;
    s16x8 pk0, pk1;
#pragma unroll
    for (int n = 0; n < 8; ++n) pk0[n] = (short)f32_to_bf16_rtn(acc[n]);
#pragma unroll
    for (int n = 0; n < 8; ++n) pk1[n] = (short)f32_to_bf16_rtn(acc[n + 8]);
    *(s16x8*)hb         = pk0;
    *(s16x8*)(hb + 128) = pk1;
}

// K2: fused masked softmax + aggregation (unchanged, best measured variant):
// 32 i-rows/block, 4 waves (j-quarters), er12+masks in LDS, dist-1 B-frag
// register prefetch, (256,3), XCD-residency pin, nt out stores.
#define MSTRIDE 68   // mask LDS row stride (u32): 2-way banks (free)

__global__ __launch_bounds__(256, 3) void k2_attn(
    const uint32_t* __restrict__ abits32, const u16* __restrict__ hB,
    const float* __restrict__ el, const f32x2* __restrict__ er12,
    float* __restrict__ out)
{
    __shared__ __align__(16) char smem[33792];   // max(er 16K + mask 8.5K, racc 33K)
    float*    er_lds   = (float*)smem;           // [2048][2] floats
    uint32_t* mask_lds = (uint32_t*)(smem + 16384); // [32][MSTRIDE]
    float*    racc     = (float*)smem;           // alias (after barrier)

    const int t = threadIdx.x;
    const int jq = t >> 6, l = t & 63;
    const int o = blockIdx.x;
    const int kblk = o >> 3;                 // 0..127
    const int bw = (o & 7) + 8 * (kblk & 1); // (b,w) pair, pinned to xcd o&7
    const int b = bw >> 2;
    const int w = bw & 3;
    const int i0 = (kblk >> 1) * 32;
    const int r = l & 15;                 // A row / D col
    const int kb = l >> 4;                // k-slice 0..3
    const int ks = kb * 8;
    const int irow0 = i0 + r, irow1 = irow0 + 16;

    // ---- stage er12 (16 KB) + masks (8 KB, padded rows) into LDS ----
    {
        const f32x4* gsrc = (const f32x4*)(er12 + (size_t)(b * NH + w) * NN);
        f32x4* edst = (f32x4*)er_lds;
#pragma unroll
        for (int p = 0; p < 4; ++p) edst[t + p * 256] = gsrc[t + p * 256];
        const i32x4* msrc = (const i32x4*)(abits32 + ((size_t)b * NN + i0) * 64);
        i32x4 mv0 = msrc[t * 2];
        i32x4 mv1 = msrc[t * 2 + 1];
        const int mrow = t >> 3, mc = (t & 7) * 8;
        *(i32x4*)&mask_lds[mrow * MSTRIDE + mc]     = mv0;
        *(i32x4*)&mask_lds[mrow * MSTRIDE + mc + 4] = mv1;
    }

    const u16* hbp = hB + ((((size_t)b * 64 + jq * 16) * 4 + w) * 4) * 512 + (size_t)l * 8;
    const float eli0 = el[((size_t)b * NH + w) * NN + irow0];
    const float eli1 = el[((size_t)b * NH + w) * NN + irow1];
    const float E1i0 = exp2_fast(eli0), E2i0 = exp2_fast(0.2f * eli0);
    const float E1i1 = exp2_fast(eli1), E2i1 = exp2_fast(0.2f * eli1);

    f32x4 a00 = {0.f,0.f,0.f,0.f}, a01 = a00, a02 = a00, a03 = a00, as0 = a00;
    f32x4 a10 = a00, a11 = a00, a12 = a00, a13 = a00, as1 = a00;
    s16x8 ones;
#pragma unroll
    for (int k = 0; k < 8; ++k) ones[k] = (short)0x3F80;   // bf16 1.0

    // prologue: iter-0 B-frags
    s16x8 b0c = *(const s16x8*)(hbp + 0 * 512);
    s16x8 b1c = *(const s16x8*)(hbp + 1 * 512);
    s16x8 b2c = *(const s16x8*)(hbp + 2 * 512);
    s16x8 b3c = *(const s16x8*)(hbp + 3 * 512);
    __syncthreads();   // staging complete

#define MFMA_BF16 __builtin_amdgcn_mfma_f32_16x16x32_bf16
#define BODY(IT, PF)                                                          \
    {                                                                         \
        const int itv = (IT);                                                 \
        const int jb2 = (jq * 512 + itv * 32 + ks) * 2;                       \
        f32x4 e0 = *(const f32x4*)(er_lds + jb2);                             \
        f32x4 e1 = *(const f32x4*)(er_lds + jb2 + 4);                         \
        f32x4 e2 = *(const f32x4*)(er_lds + jb2 + 8);                         \
        f32x4 e3 = *(const f32x4*)(er_lds + jb2 + 12);                        \
        uint32_t w2a = mask_lds[r * MSTRIDE + jq * 16 + itv] >> ks;           \
        uint32_t w2b = mask_lds[(16 + r) * MSTRIDE + jq * 16 + itv] >> ks;    \
        s16x8 b0n, b1n, b2n, b3n;                                             \
        if (PF) {                                                             \
            const u16* hp_ = hbp + (size_t)(itv + 1) * 8192;                  \
            b0n = *(const s16x8*)(hp_ + 0 * 512);                             \
            b1n = *(const s16x8*)(hp_ + 1 * 512);                             \
            b2n = *(const s16x8*)(hp_ + 2 * 512);                             \
            b3n = *(const s16x8*)(hp_ + 3 * 512);                             \
        }                                                                     \
        __builtin_amdgcn_sched_barrier(0);                                    \
        union { s16x8 v; uint32_t u[4]; } afa, afb;                           \
        _Pragma("unroll")                                                     \
        for (int kk = 0; kk < 4; ++kk) {                                      \
            f32x4 ev = (kk == 0) ? e0 : ((kk == 1) ? e1 : ((kk == 2) ? e2 : e3)); \
            float t00 = E1i0 * ev[0], m00 = E2i0 * ev[1];                     \
            float t01 = E1i0 * ev[2], m01 = E2i0 * ev[3];                     \
            float t10 = E1i1 * ev[0], m10 = E2i1 * ev[1];                     \
            float t11 = E1i1 * ev[2], m11 = E2i1 * ev[3];                     \
            float p00 = fmaxf(t00, m00);   /* = (s>=0)?2^s:2^(0.2s) */        \
            float p01 = fmaxf(t01, m01);                                      \
            float p10 = fmaxf(t10, m10);                                      \
            float p11 = fmaxf(t11, m11);                                      \
            union { float f; uint32_t u; } c00, c01, c10, c11;                \
            c00.f = p00; c01.f = p01; c10.f = p10; c11.f = p11;               \
            uint32_t q00 = c00.u & (uint32_t)sbfe1(w2a, 2 * kk);              \
            uint32_t q01 = c01.u & (uint32_t)sbfe1(w2a, 2 * kk + 1);          \
            uint32_t q10 = c10.u & (uint32_t)sbfe1(w2b, 2 * kk);              \
            uint32_t q11 = c11.u & (uint32_t)sbfe1(w2b, 2 * kk + 1);          \
            afa.u[kk] = __builtin_amdgcn_perm(q01, q00, 0x07060302);          \
            afb.u[kk] = __builtin_amdgcn_perm(q11, q10, 0x07060302);          \
        }                                                                     \
        a00 = MFMA_BF16(afa.v, b0c, a00, 0, 0, 0);                            \
        a01 = MFMA_BF16(afa.v, b1c, a01, 0, 0, 0);                            \
        a02 = MFMA_BF16(afa.v, b2c, a02, 0, 0, 0);                            \
        a03 = MFMA_BF16(afa.v, b3c, a03, 0, 0, 0);                            \
        as0 = MFMA_BF16(afa.v, ones, as0, 0, 0, 0);                           \
        a10 = MFMA_BF16(afb.v, b0c, a10, 0, 0, 0);                            \
        a11 = MFMA_BF16(afb.v, b1c, a11, 0, 0, 0);                            \
        a12 = MFMA_BF16(afb.v, b2c, a12, 0, 0, 0);                            \
        a13 = MFMA_BF16(afb.v, b3c, a13, 0, 0, 0);                            \
        as1 = MFMA_BF16(afb.v, ones, as1, 0, 0, 0);                           \
        if (PF) { b0c = b0n; b1c = b1n; b2c = b2n; b3c = b3n; }               \
    }

    for (int g = 0; g < 3; ++g) {
#pragma unroll
        for (int s = 0; s < 4; ++s) BODY(g * 4 + s, 1);
    }
    BODY(12, 1); BODY(13, 1); BODY(14, 1); BODY(15, 0);

    // ---- cross-jq reduce through LDS (racc aliases er/mask region) ----
    __syncthreads();   // all waves done reading er_lds/mask_lds
    if (jq > 0) {
        float* p = &racc[((jq - 1) * 64 + l) * 44];
        *(f32x4*)(p +  0) = a00; *(f32x4*)(p +  4) = a01;
        *(f32x4*)(p +  8) = a02; *(f32x4*)(p + 12) = a03;
        *(f32x4*)(p + 16) = as0;
        *(f32x4*)(p + 20) = a10; *(f32x4*)(p + 24) = a11;
        *(f32x4*)(p + 28) = a12; *(f32x4*)(p + 32) = a13;
        *(f32x4*)(p + 36) = as1;
    }
    __syncthreads();
    if (jq == 0) {
#pragma unroll
        for (int s = 0; s < 3; ++s) {
            const float* p = &racc[(s * 64 + l) * 44];
            a00 += *(const f32x4*)(p +  0); a01 += *(const f32x4*)(p +  4);
            a02 += *(const f32x4*)(p +  8); a03 += *(const f32x4*)(p + 12);
            as0 += *(const f32x4*)(p + 16);
            a10 += *(const f32x4*)(p + 20); a11 += *(const f32x4*)(p + 24);
            a12 += *(const f32x4*)(p + 28); a13 += *(const f32x4*)(p + 32);
            as1 += *(const f32x4*)(p + 36);
        }

        float* op = out + ((size_t)b * NN + i0) * F_OUT + w * HD;
#pragma unroll
        for (int q = 0; q < 4; ++q) {
            const int row0 = kb * 4 + q;
            float inv0 = 1.0f / as0[q];
            __builtin_nontemporal_store(a00[q] * inv0, &op[(size_t)row0 * F_OUT +  0 + r]);
            __builtin_nontemporal_store(a01[q] * inv0, &op[(size_t)row0 * F_OUT + 16 + r]);
            __builtin_nontemporal_store(a02[q] * inv0, &op[(size_t)row0 * F_OUT + 32 + r]);
            __builtin_nontemporal_store(a03[q] * inv0, &op[(size_t)row0 * F_OUT + 48 + r]);
            const int row1 = 16 + kb * 4 + q;
            float inv1 = 1.0f / as1[q];
            __builtin_nontemporal_store(a10[q] * inv1, &op[(size_t)row1 * F_OUT +  0 + r]);
            __builtin_nontemporal_store(a11[q] * inv1, &op[(size_t)row1 * F_OUT + 16 + r]);
            __builtin_nontemporal_store(a12[q] * inv1, &op[(size_t)row1 * F_OUT + 32 + r]);
            __builtin_nontemporal_store(a13[q] * inv1, &op[(size_t)row1 * F_OUT + 48 + r]);
        }
    }
}

extern "C" void kernel_launch(void* const* d_in, const int* in_sizes, int n_in,
                              void* d_out, int out_size, void* d_ws, size_t ws_size,
                              hipStream_t stream) {
    const float* x   = (const float*)d_in[0];
    const int*   adj = (const int*)d_in[1];
    const float* W   = (const float*)d_in[2];
    const float* a_l = (const float*)d_in[3];
    const float* a_r = (const float*)d_in[4];
    float* out = (float*)d_out;

    char* ws = (char*)d_ws;
    u16*      hB      = (u16*)ws;                                        // 4 MB
    uint32_t* abits32 = (uint32_t*)(ws + (size_t)BB * F_OUT * NN * 2);   // 2 MB
    float*    el      = (float*)(ws + (size_t)BB * F_OUT * NN * 2 + (size_t)BB * NN * 256);
    f32x2*    er12    = (f32x2*)(el + (size_t)BB * NH * NN);

    k0_pack<<<BB * NN / 4, 256, 0, stream>>>(adj, abits32);
    k1_proj<<<BB * (NN / 16), 256, 0, stream>>>(x, W, a_l, a_r, hB, el, er12);
    k2_attn<<<BB * NH * (NN / 32), 256, 0, stream>>>(abits32, hB, el, er12, out);
}

// Round 18
// 45.077 us; speedup vs baseline: 1.5479x; 1.5479x over previous
//
#include <hip/hip_runtime.h>
#include <stdint.h>

#define BB 4
#define NN 2048
#define F_IN 128
#define F_OUT 256
#define NH 4
#define HD 64

typedef float f32x4 __attribute__((ext_vector_type(4)));
typedef float f32x2 __attribute__((ext_vector_type(2)));
typedef short s16x8 __attribute__((ext_vector_type(8)));
typedef int i32x4 __attribute__((ext_vector_type(4)));
typedef unsigned int u32x2 __attribute__((ext_vector_type(2)));
typedef unsigned long long u64;
typedef unsigned short u16;

#define LOG2E 1.4426950408889634f

__device__ __forceinline__ u16 f32_to_bf16_rtn(float f) {
    union { float f; uint32_t u; } v; v.f = f;
    uint32_t u = v.u;
    u += 0x7fffu + ((u >> 16) & 1u);
    return (u16)(u >> 16);
}

__device__ __forceinline__ float exp2_fast(float x) {
#if __has_builtin(__builtin_amdgcn_exp2f)
    return __builtin_amdgcn_exp2f(x);
#else
    return exp2f(x);
#endif
}

__device__ __forceinline__ int sbfe1(uint32_t v, int k) {
#if __has_builtin(__builtin_amdgcn_sbfe)
    return __builtin_amdgcn_sbfe((int)v, k, 1);   // bit k sign-extended: 0 or -1
#else
    return ((int32_t)(v << (31 - k))) >> 31;
#endif
}

__device__ __forceinline__ s16x8 pack_bf16x8(f32x4 a, f32x4 b) {
    union { s16x8 v; u16 h[8]; } pk;
    pk.h[0] = f32_to_bf16_rtn(a[0]); pk.h[1] = f32_to_bf16_rtn(a[1]);
    pk.h[2] = f32_to_bf16_rtn(a[2]); pk.h[3] = f32_to_bf16_rtn(a[3]);
    pk.h[4] = f32_to_bf16_rtn(b[0]); pk.h[5] = f32_to_bf16_rtn(b[1]);
    pk.h[6] = f32_to_bf16_rtn(b[2]); pk.h[7] = f32_to_bf16_rtn(b[3]);
    return pk.v;
}

#define MFMA_BF16 __builtin_amdgcn_mfma_f32_16x16x32_bf16

// K01: adj-pack (memory-bound) + MFMA projection (compute-tiny), interleaved
// (proj = every 5th block). Proj: 16-row tile, 4 waves = 4 heads; x staged
// as bf16 A-frags (1 ds_write_b128/thread), W converted in-register to
// B-frags (L1-resident), 16 MFMA/wave; el/er via shfl-reduce; hB via a
// small padded LDS bounce (layout identical to previous -> k2 unchanged).
__global__ __launch_bounds__(256) void k01(
    const int* __restrict__ adj, const float* __restrict__ x,
    const float* __restrict__ W, const float* __restrict__ a_l,
    const float* __restrict__ a_r, uint32_t* __restrict__ abits32,
    u16* __restrict__ hB, float* __restrict__ el, f32x2* __restrict__ er12)
{
    const int t = threadIdx.x;
    __shared__ __align__(16) u16 psmem[2048 + 256 * 24];   // xA 4KB + h_lds 12KB

    const int bid = blockIdx.x;
    if ((bid % 5) != 4) {
        // ---- pack: wave = row; dwordx4 loads, nibble + shfl OR-tree ----
        const int pack_id = bid - (bid + 1) / 5;        // 0..2047
        const int row = (pack_id << 2) | (t >> 6);
        const int l = t & 63;
        const i32x4* rowp = (const i32x4*)(adj + (size_t)row * NN) + l;
        i32x4 v[8];
#pragma unroll
        for (int u = 0; u < 8; ++u) v[u] = rowp[u * 64];   // all 8 in flight
        const int sh = (l & 7) * 4;
        uint32_t w[8];
#pragma unroll
        for (int u = 0; u < 8; ++u) {
            uint32_t nib = (uint32_t)(v[u][0] != 0)
                         | ((uint32_t)(v[u][1] != 0) << 1)
                         | ((uint32_t)(v[u][2] != 0) << 2)
                         | ((uint32_t)(v[u][3] != 0) << 3);
            uint32_t xv = nib << sh;
            xv |= __shfl_xor(xv, 1, 64);
            xv |= __shfl_xor(xv, 2, 64);
            xv |= __shfl_xor(xv, 4, 64);
            w[u] = xv;
        }
        abits32[(size_t)row * 64 + (l & 7) * 8 + (l >> 3)] = w[l & 7];
        return;
    }

    // ---- proj (MFMA): 16 n-rows, wave w = head w (64 o-cols) ----
    u16* xA    = psmem;           // [4 kt][64 lane][8] bf16 A-frags
    u16* h_lds = psmem + 2048;    // [256 o][24] bf16 (stride 24: aligned + 2-way banks)

    const int proj_id = bid / 5;
    const int b = proj_id >> 7;
    const int n0 = (proj_id & 127) * 16;
    const int w = t >> 6, l = t & 63;

    // stage x tile -> bf16 A-frags (coalesced 32B/thread, one b128 LDS write)
    {
        const int n = t >> 4, kg = t & 15;
        const float* xp = x + ((size_t)b * NN + n0 + n) * F_IN + kg * 8;
        f32x4 xa = *(const f32x4*)xp;
        f32x4 xb = *(const f32x4*)(xp + 4);
        *(s16x8*)(xA + (size_t)((kg >> 2) * 64 + n + 16 * (kg & 3)) * 8) =
            pack_bf16x8(xa, xb);
    }
    __syncthreads();

    // A-frags for this wave
    s16x8 A0 = *(const s16x8*)(xA + (size_t)(0 * 64 + l) * 8);
    s16x8 A1 = *(const s16x8*)(xA + (size_t)(1 * 64 + l) * 8);
    s16x8 A2 = *(const s16x8*)(xA + (size_t)(2 * 64 + l) * 8);
    s16x8 A3 = *(const s16x8*)(xA + (size_t)(3 * 64 + l) * 8);

    f32x4 acc[4];
#pragma unroll
    for (int ot = 0; ot < 4; ++ot) acc[ot] = (f32x4){0.f, 0.f, 0.f, 0.f};

#pragma unroll
    for (int ot = 0; ot < 4; ++ot) {
        const float* wbase = W + ((size_t)(w * 64 + ot * 16 + (l & 15))) * F_IN + (l >> 4) * 8;
#pragma unroll
        for (int kt = 0; kt < 4; ++kt) {
            const float* wp = wbase + kt * 32;
            f32x4 wa = *(const f32x4*)wp;
            f32x4 wb = *(const f32x4*)(wp + 4);
            s16x8 bw = pack_bf16x8(wa, wb);
            s16x8 Af = (kt == 0) ? A0 : ((kt == 1) ? A1 : ((kt == 2) ? A2 : A3));
            acc[ot] = MFMA_BF16(Af, bw, acc[ot], 0, 0, 0);
        }
    }
    // lane l holds D[n = (l>>4)*4+q][o = w*64 + ot*16 + (l&15)]

    // el / er12 via in-register reduce over the 16 lanes sharing (l>>4)
    {
        float alv[4], arv[4];
#pragma unroll
        for (int ot = 0; ot < 4; ++ot) {
            alv[ot] = a_l[w * 64 + ot * 16 + (l & 15)];
            arv[ot] = a_r[w * 64 + ot * 16 + (l & 15)];
        }
        float vL[4], vR[4];
#pragma unroll
        for (int q = 0; q < 4; ++q) {
            vL[q] = acc[0][q] * alv[0] + acc[1][q] * alv[1]
                  + acc[2][q] * alv[2] + acc[3][q] * alv[3];
            vR[q] = acc[0][q] * arv[0] + acc[1][q] * arv[1]
                  + acc[2][q] * arv[2] + acc[3][q] * arv[3];
        }
#pragma unroll
        for (int off = 1; off < 16; off <<= 1) {
#pragma unroll
            for (int q = 0; q < 4; ++q) {
                vL[q] += __shfl_xor(vL[q], off, 64);
                vR[q] += __shfl_xor(vR[q], off, 64);
            }
        }
        if ((l & 15) == 0) {
#pragma unroll
            for (int q = 0; q < 4; ++q) {
                const int n = n0 + (l >> 4) * 4 + q;
                el[((size_t)b * NH + w) * NN + n] = vL[q] * LOG2E;
                float sre = vR[q] * LOG2E;
                f32x2 v2; v2[0] = exp2_fast(sre); v2[1] = exp2_fast(0.2f * sre);
                er12[((size_t)b * NH + w) * NN + n] = v2;
            }
        }
    }

    // h -> LDS bounce (bf16), then store hB in k2's B-frag layout
#pragma unroll
    for (int ot = 0; ot < 4; ++ot) {
        union { u32x2 d; u16 h[4]; } pq;
#pragma unroll
        for (int q = 0; q < 4; ++q) pq.h[q] = f32_to_bf16_rtn(acc[ot][q]);
        *(u32x2*)(h_lds + (size_t)(w * 64 + ot * 16 + (l & 15)) * 24 + (l >> 4) * 4) = pq.d;
    }
    __syncthreads();
    {
        const int dcol = t & 15, cb = (t >> 4) & 3, hw = t >> 6;
        const u16* src = h_lds + (size_t)(hw * 64 + cb * 16 + dcol) * 24;
        s16x8 g0 = *(const s16x8*)src;        // n0 + 0..7
        s16x8 g1 = *(const s16x8*)(src + 8);  // n0 + 8..15
        const int j8 = (n0 >> 3) & 2;
        u16* hb = hB + ((((size_t)b * 64 + (n0 >> 5)) * 4 + hw) * 4 + cb) * 512;
        *(s16x8*)(hb + (size_t)(dcol + 16 * j8) * 8)       = g0;
        *(s16x8*)(hb + (size_t)(dcol + 16 * (j8 + 1)) * 8) = g1;
    }
}

// K2: fused masked softmax + aggregation (unchanged, best measured variant):
// 32 i-rows/block, 4 waves (j-quarters), er12+masks in LDS, dist-1 B-frag
// register prefetch, (256,3), XCD-residency pin, nt out stores.
#define MSTRIDE 68   // mask LDS row stride (u32): 2-way banks (free)

__global__ __launch_bounds__(256, 3) void k2_attn(
    const uint32_t* __restrict__ abits32, const u16* __restrict__ hB,
    const float* __restrict__ el, const f32x2* __restrict__ er12,
    float* __restrict__ out)
{
    __shared__ __align__(16) char smem[33792];   // max(er 16K + mask 8.5K, racc 33K)
    float*    er_lds   = (float*)smem;           // [2048][2] floats
    uint32_t* mask_lds = (uint32_t*)(smem + 16384); // [32][MSTRIDE]
    float*    racc     = (float*)smem;           // alias (after barrier)

    const int t = threadIdx.x;
    const int jq = t >> 6, l = t & 63;
    const int o = blockIdx.x;
    const int kblk = o >> 3;                 // 0..127
    const int bw = (o & 7) + 8 * (kblk & 1); // (b,w) pair, pinned to xcd o&7
    const int b = bw >> 2;
    const int w = bw & 3;
    const int i0 = (kblk >> 1) * 32;
    const int r = l & 15;                 // A row / D col
    const int kb = l >> 4;                // k-slice 0..3
    const int ks = kb * 8;
    const int irow0 = i0 + r, irow1 = irow0 + 16;

    // ---- stage er12 (16 KB) + masks (8 KB, padded rows) into LDS ----
    {
        const f32x4* gsrc = (const f32x4*)(er12 + (size_t)(b * NH + w) * NN);
        f32x4* edst = (f32x4*)er_lds;
#pragma unroll
        for (int p = 0; p < 4; ++p) edst[t + p * 256] = gsrc[t + p * 256];
        const i32x4* msrc = (const i32x4*)(abits32 + ((size_t)b * NN + i0) * 64);
        i32x4 mv0 = msrc[t * 2];
        i32x4 mv1 = msrc[t * 2 + 1];
        const int mrow = t >> 3, mc = (t & 7) * 8;
        *(i32x4*)&mask_lds[mrow * MSTRIDE + mc]     = mv0;
        *(i32x4*)&mask_lds[mrow * MSTRIDE + mc + 4] = mv1;
    }

    const u16* hbp = hB + ((((size_t)b * 64 + jq * 16) * 4 + w) * 4) * 512 + (size_t)l * 8;
    const float eli0 = el[((size_t)b * NH + w) * NN + irow0];
    const float eli1 = el[((size_t)b * NH + w) * NN + irow1];
    const float E1i0 = exp2_fast(eli0), E2i0 = exp2_fast(0.2f * eli0);
    const float E1i1 = exp2_fast(eli1), E2i1 = exp2_fast(0.2f * eli1);

    f32x4 a00 = {0.f,0.f,0.f,0.f}, a01 = a00, a02 = a00, a03 = a00, as0 = a00;
    f32x4 a10 = a00, a11 = a00, a12 = a00, a13 = a00, as1 = a00;
    s16x8 ones;
#pragma unroll
    for (int k = 0; k < 8; ++k) ones[k] = (short)0x3F80;   // bf16 1.0

    // prologue: iter-0 B-frags
    s16x8 b0c = *(const s16x8*)(hbp + 0 * 512);
    s16x8 b1c = *(const s16x8*)(hbp + 1 * 512);
    s16x8 b2c = *(const s16x8*)(hbp + 2 * 512);
    s16x8 b3c = *(const s16x8*)(hbp + 3 * 512);
    __syncthreads();   // staging complete

#define BODY(IT, PF)                                                          \
    {                                                                         \
        const int itv = (IT);                                                 \
        const int jb2 = (jq * 512 + itv * 32 + ks) * 2;                       \
        f32x4 e0 = *(const f32x4*)(er_lds + jb2);                             \
        f32x4 e1 = *(const f32x4*)(er_lds + jb2 + 4);                         \
        f32x4 e2 = *(const f32x4*)(er_lds + jb2 + 8);                         \
        f32x4 e3 = *(const f32x4*)(er_lds + jb2 + 12);                        \
        uint32_t w2a = mask_lds[r * MSTRIDE + jq * 16 + itv] >> ks;           \
        uint32_t w2b = mask_lds[(16 + r) * MSTRIDE + jq * 16 + itv] >> ks;    \
        s16x8 b0n, b1n, b2n, b3n;                                             \
        if (PF) {                                                             \
            const u16* hp_ = hbp + (size_t)(itv + 1) * 8192;                  \
            b0n = *(const s16x8*)(hp_ + 0 * 512);                             \
            b1n = *(const s16x8*)(hp_ + 1 * 512);                             \
            b2n = *(const s16x8*)(hp_ + 2 * 512);                             \
            b3n = *(const s16x8*)(hp_ + 3 * 512);                             \
        }                                                                     \
        __builtin_amdgcn_sched_barrier(0);                                    \
        union { s16x8 v; uint32_t u[4]; } afa, afb;                           \
        _Pragma("unroll")                                                     \
        for (int kk = 0; kk < 4; ++kk) {                                      \
            f32x4 ev = (kk == 0) ? e0 : ((kk == 1) ? e1 : ((kk == 2) ? e2 : e3)); \
            float t00 = E1i0 * ev[0], m00 = E2i0 * ev[1];                     \
            float t01 = E1i0 * ev[2], m01 = E2i0 * ev[3];                     \
            float t10 = E1i1 * ev[0], m10 = E2i1 * ev[1];                     \
            float t11 = E1i1 * ev[2], m11 = E2i1 * ev[3];                     \
            float p00 = fmaxf(t00, m00);   /* = (s>=0)?2^s:2^(0.2s) */        \
            float p01 = fmaxf(t01, m01);                                      \
            float p10 = fmaxf(t10, m10);                                      \
            float p11 = fmaxf(t11, m11);                                      \
            union { float f; uint32_t u; } c00, c01, c10, c11;                \
            c00.f = p00; c01.f = p01; c10.f = p10; c11.f = p11;               \
            uint32_t q00 = c00.u & (uint32_t)sbfe1(w2a, 2 * kk);              \
            uint32_t q01 = c01.u & (uint32_t)sbfe1(w2a, 2 * kk + 1);          \
            uint32_t q10 = c10.u & (uint32_t)sbfe1(w2b, 2 * kk);              \
            uint32_t q11 = c11.u & (uint32_t)sbfe1(w2b, 2 * kk + 1);          \
            afa.u[kk] = __builtin_amdgcn_perm(q01, q00, 0x07060302);          \
            afb.u[kk] = __builtin_amdgcn_perm(q11, q10, 0x07060302);          \
        }                                                                     \
        a00 = MFMA_BF16(afa.v, b0c, a00, 0, 0, 0);                            \
        a01 = MFMA_BF16(afa.v, b1c, a01, 0, 0, 0);                            \
        a02 = MFMA_BF16(afa.v, b2c, a02, 0, 0, 0);                            \
        a03 = MFMA_BF16(afa.v, b3c, a03, 0, 0, 0);                            \
        as0 = MFMA_BF16(afa.v, ones, as0, 0, 0, 0);                           \
        a10 = MFMA_BF16(afb.v, b0c, a10, 0, 0, 0);                            \
        a11 = MFMA_BF16(afb.v, b1c, a11, 0, 0, 0);                            \
        a12 = MFMA_BF16(afb.v, b2c, a12, 0, 0, 0);                            \
        a13 = MFMA_BF16(afb.v, b3c, a13, 0, 0, 0);                            \
        as1 = MFMA_BF16(afb.v, ones, as1, 0, 0, 0);                           \
        if (PF) { b0c = b0n; b1c = b1n; b2c = b2n; b3c = b3n; }               \
    }

    for (int g = 0; g < 3; ++g) {
#pragma unroll
        for (int s = 0; s < 4; ++s) BODY(g * 4 + s, 1);
    }
    BODY(12, 1); BODY(13, 1); BODY(14, 1); BODY(15, 0);

    // ---- cross-jq reduce through LDS (racc aliases er/mask region) ----
    __syncthreads();   // all waves done reading er_lds/mask_lds
    if (jq > 0) {
        float* p = &racc[((jq - 1) * 64 + l) * 44];
        *(f32x4*)(p +  0) = a00; *(f32x4*)(p +  4) = a01;
        *(f32x4*)(p +  8) = a02; *(f32x4*)(p + 12) = a03;
        *(f32x4*)(p + 16) = as0;
        *(f32x4*)(p + 20) = a10; *(f32x4*)(p + 24) = a11;
        *(f32x4*)(p + 28) = a12; *(f32x4*)(p + 32) = a13;
        *(f32x4*)(p + 36) = as1;
    }
    __syncthreads();
    if (jq == 0) {
#pragma unroll
        for (int s = 0; s < 3; ++s) {
            const float* p = &racc[(s * 64 + l) * 44];
            a00 += *(const f32x4*)(p +  0); a01 += *(const f32x4*)(p +  4);
            a02 += *(const f32x4*)(p +  8); a03 += *(const f32x4*)(p + 12);
            as0 += *(const f32x4*)(p + 16);
            a10 += *(const f32x4*)(p + 20); a11 += *(const f32x4*)(p + 24);
            a12 += *(const f32x4*)(p + 28); a13 += *(const f32x4*)(p + 32);
            as1 += *(const f32x4*)(p + 36);
        }

        float* op = out + ((size_t)b * NN + i0) * F_OUT + w * HD;
#pragma unroll
        for (int q = 0; q < 4; ++q) {
            const int row0 = kb * 4 + q;
            float inv0 = 1.0f / as0[q];
            __builtin_nontemporal_store(a00[q] * inv0, &op[(size_t)row0 * F_OUT +  0 + r]);
            __builtin_nontemporal_store(a01[q] * inv0, &op[(size_t)row0 * F_OUT + 16 + r]);
            __builtin_nontemporal_store(a02[q] * inv0, &op[(size_t)row0 * F_OUT + 32 + r]);
            __builtin_nontemporal_store(a03[q] * inv0, &op[(size_t)row0 * F_OUT + 48 + r]);
            const int row1 = 16 + kb * 4 + q;
            float inv1 = 1.0f / as1[q];
            __builtin_nontemporal_store(a10[q] * inv1, &op[(size_t)row1 * F_OUT +  0 + r]);
            __builtin_nontemporal_store(a11[q] * inv1, &op[(size_t)row1 * F_OUT + 16 + r]);
            __builtin_nontemporal_store(a12[q] * inv1, &op[(size_t)row1 * F_OUT + 32 + r]);
            __builtin_nontemporal_store(a13[q] * inv1, &op[(size_t)row1 * F_OUT + 48 + r]);
        }
    }
}

extern "C" void kernel_launch(void* const* d_in, const int* in_sizes, int n_in,
                              void* d_out, int out_size, void* d_ws, size_t ws_size,
                              hipStream_t stream) {
    const float* x   = (const float*)d_in[0];
    const int*   adj = (const int*)d_in[1];
    const float* W   = (const float*)d_in[2];
    const float* a_l = (const float*)d_in[3];
    const float* a_r = (const float*)d_in[4];
    float* out = (float*)d_out;

    char* ws = (char*)d_ws;
    u16*      hB      = (u16*)ws;                                        // 4 MB
    uint32_t* abits32 = (uint32_t*)(ws + (size_t)BB * F_OUT * NN * 2);   // 2 MB
    float*    el      = (float*)(ws + (size_t)BB * F_OUT * NN * 2 + (size_t)BB * NN * 256);
    f32x2*    er12    = (f32x2*)(el + (size_t)BB * NH * NN);

    k01<<<2560, 256, 0, stream>>>(adj, x, W, a_l, a_r, abits32, hB, el, er12);
    k2_attn<<<BB * NH * (NN / 32), 256, 0, stream>>>(abits32, hB, el, er12, out);
}